// Round 9
// baseline (1057.283 us; speedup 1.0000x reference)
//
#include <hip/hip_runtime.h>

#define NNODES 100000
#define NEDGES 1600000
#define BN_EPS 1e-5f
#define L2_EPS 1e-12f

#define BKT_SHIFT 9
#define BKT_SIZE  512
#define NBKT      196            // ceil(100000/512)
#define CHUNK     4096
#define NBLK_E    391            // ceil(1600000/4096)
#define NSLOT     64             // BN-stats shard count
#define NPB       64             // nodes per layer tile
#define NLBLK     1563           // ceil(100000/64)
#define NBLKG     512            // grid: 2 blocks/CU resource-guaranteed resident
#define SRCMASK   0x03FFFFFFu

// ---------------------------------------------------------------------------
struct LayerSM {
    float acc[NPB * 17];         // max CILp = 17
    float sWl[32 * 17];
    float sWr[32 * 17];
    float sBl[32];
    float sSc[16];
    float sSh[16];
    int   sRP[NPB + 1];
    float sSumR[16];
    float sSqR[16];
    float red_sum[32];
    float red_sq[32];
};
struct BuildSM {
    int a[512];
    int b[512];
    int wsum[8];
    int beg, end;
};
union SMem {
    LayerSM layer;
    BuildSM build;
    int h[NBKT];
};

// ---------------------------------------------------------------------------
// Device-scope grid barrier (generation counter). Regular-launch-safe
// replacement for cooperative grid.sync(). __threadfence() on the release
// side writes back this XCD's L2; on the acquire side invalidates caches —
// required for cross-XCD visibility of normal stores (G16).
__device__ __forceinline__ void grid_sync(unsigned* bar, unsigned* gen) {
    __syncthreads();
    if (threadIdx.x == 0) {
        __threadfence();
        unsigned g = __hip_atomic_load(gen, __ATOMIC_RELAXED, __HIP_MEMORY_SCOPE_AGENT);
        unsigned prev = __hip_atomic_fetch_add(bar, 1u, __ATOMIC_ACQ_REL, __HIP_MEMORY_SCOPE_AGENT);
        if (prev == NBLKG - 1) {
            __hip_atomic_store(bar, 0u, __ATOMIC_RELAXED, __HIP_MEMORY_SCOPE_AGENT);
            __hip_atomic_fetch_add(gen, 1u, __ATOMIC_RELEASE, __HIP_MEMORY_SCOPE_AGENT);
        } else {
            while (__hip_atomic_load(gen, __ATOMIC_ACQUIRE, __HIP_MEMORY_SCOPE_AGENT) == g)
                __builtin_amdgcn_s_sleep(8);
        }
        __threadfence();
    }
    __syncthreads();
}

__global__ void init_barrier(unsigned* bar) {
    if (threadIdx.x < 2) bar[threadIdx.x] = 0u;
}

// ---------------------------------------------------------------------------
// Wave-level block exclusive scan (512 threads). Leading barrier protects
// wsum (and any LDS written just before) across consecutive calls.
__device__ __forceinline__ int block_excl_scan512(int v, int* wsum) {
    __syncthreads();
    int incl = v;
#pragma unroll
    for (int off = 1; off < 64; off <<= 1) {
        int t = __shfl_up(incl, off);
        if ((threadIdx.x & 63) >= off) incl += t;
    }
    int wid = threadIdx.x >> 6;
    if ((threadIdx.x & 63) == 63) wsum[wid] = incl;
    __syncthreads();
    if (threadIdx.x < 8) {
        int w = wsum[threadIdx.x];
#pragma unroll
        for (int off = 1; off < 8; off <<= 1) {
            int t = __shfl_up(w, off);
            if ((int)threadIdx.x >= off) w += t;
        }
        wsum[threadIdx.x] = w;
    }
    __syncthreads();
    int base = wid ? wsum[wid - 1] : 0;
    return base + incl - v;
}

// ---------------------------------------------------------------------------
template<int CI>
__device__ __forceinline__ void load_row(const float* __restrict__ p, float* r) {
    constexpr int N4 = CI / 4;
#pragma unroll
    for (int i = 0; i < N4; i++) {
        float4 v = ((const float4*)p)[i];
        r[4*i] = v.x; r[4*i+1] = v.y; r[4*i+2] = v.z; r[4*i+3] = v.w;
    }
    if constexpr ((CI % 4) >= 2) {
        float2 v = ((const float2*)(p + 4 * N4))[0];
        r[4*N4] = v.x; r[4*N4+1] = v.y;
    }
    if constexpr ((CI % 2) == 1) r[CI - 1] = p[CI - 1];
}

// ---------------------------------------------------------------------------
// One fused layer phase (round-6 fp32 logic): blocked-run Phase A with
// register accumulate + flush-on-dst-change + batch-4 pipeline; node-parallel
// Phase B. Weights/affine staged once per block; block loops over tiles.
template<int CI, int CIL, int SI, int CO, int SO, bool IN_AFFINE, bool DO_STATS>
__device__ void layer_phase(LayerSM& s,
                            const int* __restrict__ row_ptr, const unsigned* __restrict__ col,
                            const float* __restrict__ h,
                            const float* __restrict__ ssum_in, const float* __restrict__ ssq_in,
                            const float* __restrict__ g_in, const float* __restrict__ b_in,
                            const float* __restrict__ wl, const float* __restrict__ bl,
                            const float* __restrict__ wr,
                            float* __restrict__ y,
                            float* __restrict__ stat_sum, float* __restrict__ stat_sq) {
    constexpr int CIp  = CI + 1;
    constexpr int CILp = CIL + 1;
    constexpr int NCH  = CIL / 4;
    constexpr int NRUN = 512 / NCH;
    constexpr int TPN  = 512 / NPB;          // 8 threads per node
    constexpr int OPT  = (CO + TPN - 1) / TPN;
    int tid = threadIdx.x;

    // ---- once per layer per block: weights + affine ----
    for (int i = tid; i < CO * CI; i += 512) {
        int o = i / CI, c = i - o * CI;
        s.sWl[o * CIp + c] = wl[i];
        s.sWr[o * CIp + c] = wr[i];
    }
    if (tid < CO) s.sBl[tid] = bl[tid];
    if (IN_AFFINE && tid < CI) { s.sSumR[tid] = 0.0f; s.sSqR[tid] = 0.0f; }
    __syncthreads();
    if (IN_AFFINE) {
        int c = tid & 31, sl = tid >> 5;
        if (c < CI) {
            float ps = 0.0f, pq = 0.0f;
#pragma unroll
            for (int sh = sl; sh < NSLOT; sh += 16) {
                ps += ssum_in[sh * 64 + c];
                pq += ssq_in[sh * 64 + c];
            }
            atomicAdd(&s.sSumR[c], ps);
            atomicAdd(&s.sSqR[c], pq);
        }
        __syncthreads();
        if (tid < CI) {
            float m  = s.sSumR[tid] * (1.0f / NNODES);
            float vv = s.sSqR[tid] * (1.0f / NNODES) - m * m;
            float sc = g_in[tid] / sqrtf(vv + BN_EPS);
            s.sSc[tid] = sc;
            s.sSh[tid] = b_in[tid] - m * sc;
        }
    }
    __syncthreads();

    for (int tile = blockIdx.x; tile < NLBLK; tile += NBLKG) {
        int first = tile * NPB;
        for (int i = tid; i < NPB * CILp; i += 512) s.acc[i] = 0.0f;
        if (tid <= NPB) s.sRP[tid] = row_ptr[min(first + tid, NNODES)];
        if (DO_STATS && tid < CO) { s.red_sum[tid] = 0.0f; s.red_sq[tid] = 0.0f; }
        __syncthreads();

        // ---- Phase A ----
        {
            int ebeg = s.sRP[0], eend = s.sRP[NPB];
            int M = eend - ebeg;
            int L = (M + NRUN - 1) / NRUN;
            int run = tid / NCH;
            int chw = (tid & (NCH - 1)) * 4;
            int e0 = ebeg + run * L;
            int se = min(e0 + L, eend);

            float racc[4] = {0.f, 0.f, 0.f, 0.f};
            int cur_d = -1;
            auto rowld = [&](unsigned c) -> float4 {
                return *(const float4*)(h + (long)(c & SRCMASK) * SI + chw);
            };
            auto flush = [&]() {
                if (cur_d >= 0) {
                    int a_ = cur_d * CILp + chw;
                    atomicAdd(&s.acc[a_ + 0], racc[0]);
                    atomicAdd(&s.acc[a_ + 1], racc[1]);
                    atomicAdd(&s.acc[a_ + 2], racc[2]);
                    atomicAdd(&s.acc[a_ + 3], racc[3]);
                }
            };
            auto accum = [&](unsigned cc, float4 rv) {
                int d_ = (int)(cc >> 26);
                if (d_ != cur_d) {
                    flush();
                    cur_d = d_;
                    racc[0] = rv.x; racc[1] = rv.y; racc[2] = rv.z; racc[3] = rv.w;
                } else {
                    racc[0] += rv.x; racc[1] += rv.y; racc[2] += rv.z; racc[3] += rv.w;
                }
            };

            unsigned cA[4], cB[4];
            float4 rA[4];
#pragma unroll
            for (int i = 0; i < 4; i++) cA[i] = (e0 + i < se) ? col[e0 + i] : 0u;
#pragma unroll
            for (int i = 0; i < 4; i++)
                rA[i] = (e0 + i < se) ? rowld(cA[i]) : make_float4(0.f, 0.f, 0.f, 0.f);
#pragma unroll
            for (int i = 0; i < 4; i++) cB[i] = (e0 + 4 + i < se) ? col[e0 + 4 + i] : 0u;

            for (int b = e0; b < se; b += 4) {
                float4 rB[4];
                unsigned cC[4];
#pragma unroll
                for (int i = 0; i < 4; i++)
                    rB[i] = (b + 4 + i < se) ? rowld(cB[i]) : make_float4(0.f, 0.f, 0.f, 0.f);
#pragma unroll
                for (int i = 0; i < 4; i++) cC[i] = (b + 8 + i < se) ? col[b + 8 + i] : 0u;
#pragma unroll
                for (int i = 0; i < 4; i++) if (b + i < se) accum(cA[i], rA[i]);
#pragma unroll
                for (int i = 0; i < 4; i++) { cA[i] = cB[i]; cB[i] = cC[i]; rA[i] = rB[i]; }
            }
            flush();
        }
        __syncthreads();

        // ---- Phase B ----
        {
            int nl = tid / TPN, t = tid & (TPN - 1);
            int node = first + nl;
            bool valid = node < NNODES;

            float outv[OPT];
            float nrm2 = 0.0f;
            if (valid) {
                int deg = s.sRP[nl + 1] - s.sRP[nl];
                float ic = 1.0f / fmaxf((float)deg, 1.0f);
                float a[CI], xin[CI];
                load_row<CI>(h + (long)node * SI, xin);
#pragma unroll
                for (int c = 0; c < CI; c++) {
                    float av = s.acc[nl * CILp + c] * ic;
                    float xv = xin[c];
                    if (IN_AFFINE) {
                        av = av * s.sSc[c] + s.sSh[c];
                        xv = xv * s.sSc[c] + s.sSh[c];
                    }
                    a[c] = av;
                    xin[c] = xv;
                }
#pragma unroll
                for (int k = 0; k < OPT; k++) {
                    int o = t * OPT + k;
                    float v = 0.0f;
                    if (o < CO) {
                        v = s.sBl[o];
#pragma unroll
                        for (int c = 0; c < CI; c++)
                            v += s.sWl[o * CIp + c] * a[c] + s.sWr[o * CIp + c] * xin[c];
                    }
                    outv[k] = v;
                    nrm2 += v * v;
                }
            }
            nrm2 += __shfl_xor(nrm2, 1);
            nrm2 += __shfl_xor(nrm2, 2);
            nrm2 += __shfl_xor(nrm2, 4);

            if (valid) {
                float inv_nrm = 1.0f / fmaxf(sqrtf(nrm2), L2_EPS);
#pragma unroll
                for (int k = 0; k < OPT; k++) {
                    int o = t * OPT + k;
                    if (o < CO) {
                        float v = fmaxf(outv[k] * inv_nrm, 0.0f);
                        y[(long)node * SO + o] = v;
                        if (DO_STATS) {
                            atomicAdd(&s.red_sum[o], v);
                            atomicAdd(&s.red_sq[o], v * v);
                        }
                    }
                }
            }
        }
        __syncthreads();

        if (DO_STATS && tid < CO) {
            int slot = tile & (NSLOT - 1);
            atomicAdd(&stat_sum[slot * 64 + tid], s.red_sum[tid]);
            atomicAdd(&stat_sq [slot * 64 + tid], s.red_sq[tid]);
        }
    }
}

// ---------------------------------------------------------------------------
struct Params {
    const float* x;
    const int*   src;
    const int*   dst;
    const float *w1l, *b1l, *w1r, *w2l, *b2l, *w2r;
    const float *w3l, *b3l, *w3r, *w4l, *b4l, *w4r;
    const float *g1, *be1, *g2, *be2, *g3, *be3;
    int*      blk_hist;
    int*      blk_off;
    int*      bucket_total;
    int*      row_ptr;
    unsigned* col;
    float*    hA;
    float*    hB;
    float*    stats;
    unsigned* staged;
    unsigned* barrier;           // [0]=bar, [1]=gen
    float*    out;
};

// ---------------------------------------------------------------------------
__global__ __launch_bounds__(512, 4) void fused_kernel(Params p) {
    __shared__ SMem sm;
    int tid = threadIdx.x;
    int bid = blockIdx.x;
    unsigned* bar = p.barrier;
    unsigned* gen = p.barrier + 1;

    // ---- phase 0: per-chunk bucket histogram (+ stats zero) ----
    if (bid < NBLK_E) {
        for (int i = tid; i < NBKT; i += 512) sm.h[i] = 0;
        __syncthreads();
        int base = bid * CHUNK;
        int end  = min(base + CHUNK, NEDGES);
        for (int e = base + tid * 4; e < end; e += 512 * 4) {
            int4 d = *reinterpret_cast<const int4*>(p.dst + e);
            atomicAdd(&sm.h[d.x >> BKT_SHIFT], 1);
            atomicAdd(&sm.h[d.y >> BKT_SHIFT], 1);
            atomicAdd(&sm.h[d.z >> BKT_SHIFT], 1);
            atomicAdd(&sm.h[d.w >> BKT_SHIFT], 1);
        }
        __syncthreads();
        for (int i = tid; i < NBKT; i += 512)
            p.blk_hist[i * NBLK_E + bid] = sm.h[i];    // [bucket][chunk]
    } else if (bid == NBLK_E) {
        for (int i = tid; i < 3 * NSLOT * 64; i += 512) p.stats[i] = 0.0f;
    }
    grid_sync(bar, gen);

    // ---- phase 1: per-bucket exclusive scan across chunks ----
    if (bid < NBKT) {
        int v = (tid < NBLK_E) ? p.blk_hist[bid * NBLK_E + tid] : 0;
        int excl = block_excl_scan512(v, sm.build.wsum);
        if (tid < NBLK_E) p.blk_off[tid * NBKT + bid] = excl;   // [chunk][bucket]
        if (tid == 511) p.bucket_total[bid] = excl + v;
    }
    grid_sync(bar, gen);

    // ---- phase 2: scatter edges into bucket segments ----
    if (bid < NBLK_E) {
        int v = (tid < NBKT) ? p.bucket_total[tid] : 0;
        int bbase = block_excl_scan512(v, sm.build.wsum);
        if (tid < NBKT) sm.build.a[tid] = bbase + p.blk_off[bid * NBKT + tid];
        __syncthreads();
        int base = bid * CHUNK;
        int end  = min(base + CHUNK, NEDGES);
        for (int e = base + tid * 4; e < end; e += 512 * 4) {
            int4 d = *reinterpret_cast<const int4*>(p.dst + e);
            int4 sc = *reinterpret_cast<const int4*>(p.src + e);
            int p0 = atomicAdd(&sm.build.a[d.x >> BKT_SHIFT], 1);
            p.staged[p0] = ((unsigned)(d.x & (BKT_SIZE - 1)) << 23) | (unsigned)sc.x;
            int p1 = atomicAdd(&sm.build.a[d.y >> BKT_SHIFT], 1);
            p.staged[p1] = ((unsigned)(d.y & (BKT_SIZE - 1)) << 23) | (unsigned)sc.y;
            int p2 = atomicAdd(&sm.build.a[d.z >> BKT_SHIFT], 1);
            p.staged[p2] = ((unsigned)(d.z & (BKT_SIZE - 1)) << 23) | (unsigned)sc.z;
            int p3 = atomicAdd(&sm.build.a[d.w >> BKT_SHIFT], 1);
            p.staged[p3] = ((unsigned)(d.w & (BKT_SIZE - 1)) << 23) | (unsigned)sc.w;
        }
    }
    grid_sync(bar, gen);

    // ---- phase 3: per-bucket CSR finalize ----
    if (bid < NBKT) {
        int* nh  = sm.build.a;
        int* cur = sm.build.b;
        nh[tid] = 0;                          // ordered by scan's leading barrier
        int v = (tid < NBKT) ? p.bucket_total[tid] : 0;
        int excl = block_excl_scan512(v, sm.build.wsum);
        if (tid == bid) { sm.build.beg = excl; sm.build.end = excl + v; }
        __syncthreads();
        int beg = sm.build.beg, end = sm.build.end;

        for (int e = beg + tid; e < end; e += 512)
            atomicAdd(&nh[p.staged[e] >> 23], 1);
        __syncthreads();

        int hv = nh[tid];
        int hexcl = block_excl_scan512(hv, sm.build.wsum);

        int node = bid * BKT_SIZE + tid;
        if (node < NNODES) p.row_ptr[node] = beg + hexcl;
        if (bid == 0 && tid == 0) p.row_ptr[NNODES] = NEDGES;
        cur[tid] = hexcl;
        __syncthreads();

        for (int e = beg + tid; e < end; e += 512) {
            unsigned pk = p.staged[e];
            int l = (int)(pk >> 23);
            int pp = atomicAdd(&cur[l], 1);
            p.col[beg + pp] = ((unsigned)(l & (NPB - 1)) << 26) | (pk & 0x7FFFFF);
        }
    }
    grid_sync(bar, gen);

    float* ssum1 = p.stats + 0 * NSLOT * 64; float* ssq1 = ssum1 + 32;
    float* ssum2 = p.stats + 1 * NSLOT * 64; float* ssq2 = ssum2 + 32;
    float* ssum3 = p.stats + 2 * NSLOT * 64; float* ssq3 = ssum3 + 32;

    // ---- layer 1: 4 -> 6 (stride 4 -> 8), +stats ----
    layer_phase<4, 4, 4, 6, 8, false, true>(sm.layer, p.row_ptr, p.col, p.x,
        nullptr, nullptr, nullptr, nullptr, p.w1l, p.b1l, p.w1r, p.hA, ssum1, ssq1);
    grid_sync(bar, gen);

    // ---- layer 2: 6 -> 8 (stride 8 -> 8), BN1 in-block, +stats ----
    layer_phase<6, 8, 8, 8, 8, true, true>(sm.layer, p.row_ptr, p.col, p.hA,
        ssum1, ssq1, p.g1, p.be1, p.w2l, p.b2l, p.w2r, p.hB, ssum2, ssq2);
    grid_sync(bar, gen);

    // ---- layer 3: 8 -> 16 (stride 8 -> 16), BN2, +stats ----
    layer_phase<8, 8, 8, 16, 16, true, true>(sm.layer, p.row_ptr, p.col, p.hB,
        ssum2, ssq2, p.g2, p.be2, p.w3l, p.b3l, p.w3r, p.hA, ssum3, ssq3);
    grid_sync(bar, gen);

    // ---- layer 4: 16 -> 32 (stride 16 -> 32), BN3, ReLU -> out ----
    layer_phase<16, 16, 16, 32, 32, true, false>(sm.layer, p.row_ptr, p.col, p.hA,
        ssum3, ssq3, p.g3, p.be3, p.w4l, p.b4l, p.w4r, p.out, nullptr, nullptr);
}

// ---------------------------------------------------------------------------
extern "C" void kernel_launch(void* const* d_in, const int* in_sizes, int n_in,
                              void* d_out, int out_size, void* d_ws, size_t ws_size,
                              hipStream_t stream) {
    const float* x   = (const float*)d_in[0];
    const int*   ei  = (const int*)d_in[1];

    char* w = (char*)d_ws;
    int* blk_hist     = (int*)w;  w += NBLK_E * NBKT * 4;
    int* blk_off      = (int*)w;  w += NBLK_E * NBKT * 4;
    int* bucket_total = (int*)w;  w += 256 * 4;
    int* row_ptr      = (int*)w;  w += (NNODES + 8) * 4;
    unsigned int* col = (unsigned int*)w; w += NEDGES * 4;
    float* hA         = (float*)w; w += NNODES * 16 * 4;
    float* hB         = (float*)w; w += NNODES * 16 * 4;   // aliased by staged
    float* stats      = (float*)w; w += 3 * NSLOT * 64 * 4;
    unsigned* barrier = (unsigned*)w; w += 64;             // own cacheline
    unsigned int* staged = (unsigned int*)hB;  // dead before hB is written

    Params p;
    p.x   = x;
    p.src = ei;
    p.dst = ei + NEDGES;
    p.w1l = (const float*)d_in[2];  p.b1l = (const float*)d_in[3];  p.w1r = (const float*)d_in[4];
    p.w2l = (const float*)d_in[5];  p.b2l = (const float*)d_in[6];  p.w2r = (const float*)d_in[7];
    p.w3l = (const float*)d_in[8];  p.b3l = (const float*)d_in[9];  p.w3r = (const float*)d_in[10];
    p.w4l = (const float*)d_in[11]; p.b4l = (const float*)d_in[12]; p.w4r = (const float*)d_in[13];
    p.g1  = (const float*)d_in[14]; p.be1 = (const float*)d_in[15];
    p.g2  = (const float*)d_in[16]; p.be2 = (const float*)d_in[17];
    p.g3  = (const float*)d_in[18]; p.be3 = (const float*)d_in[19];
    p.blk_hist = blk_hist;
    p.blk_off = blk_off;
    p.bucket_total = bucket_total;
    p.row_ptr = row_ptr;
    p.col = col;
    p.hA = hA;
    p.hB = hB;
    p.stats = stats;
    p.staged = staged;
    p.barrier = barrier;
    p.out = (float*)d_out;

    init_barrier<<<1, 64, 0, stream>>>(barrier);
    fused_kernel<<<NBLKG, 512, 0, stream>>>(p);
}

// Round 10
// 240.529 us; speedup vs baseline: 4.3957x; 4.3957x over previous
//
#include <hip/hip_runtime.h>
#include <hip/hip_fp16.h>

#define NNODES 100000
#define NEDGES 1600000
#define BN_EPS 1e-5f
#define L2_EPS 1e-12f

#define BKT_SHIFT 9
#define BKT_SIZE  512
#define NBKT      196            // ceil(100000/512)
#define CHUNK     8192
#define NBLK_E    196            // ceil(1600000/8192)
#define NSLOT     64             // BN-stats shard count

// ---------------------------------------------------------------------------
// Wave-level block exclusive scan (NT threads). Leading barrier protects wsum
// reuse across consecutive calls.
template<int NT>
__device__ __forceinline__ int block_excl_scan(int v, int* wsum) {
    __syncthreads();
    constexpr int NW = NT / 64;
    int incl = v;
#pragma unroll
    for (int off = 1; off < 64; off <<= 1) {
        int t = __shfl_up(incl, off);
        if ((threadIdx.x & 63) >= off) incl += t;
    }
    int wid = threadIdx.x >> 6;
    if ((threadIdx.x & 63) == 63) wsum[wid] = incl;
    __syncthreads();
    if (threadIdx.x < NW) {
        int w = wsum[threadIdx.x];
#pragma unroll
        for (int off = 1; off < NW; off <<= 1) {
            int t = __shfl_up(w, off);
            if ((int)threadIdx.x >= off) w += t;
        }
        wsum[threadIdx.x] = w;             // inclusive wave sums
    }
    __syncthreads();
    int base = wid ? wsum[wid - 1] : 0;
    return base + incl - v;
}

// ---------------------------------------------------------------------------
// Pass 1: per-block bucket histogram (LDS) -> transposed blk_hist. Block 0
// also zeroes the sharded BN stats accumulators.
__global__ void hist_kernel(const int* __restrict__ dst,
                            int* __restrict__ blk_hist_T, float* __restrict__ stats) {
    __shared__ int h[NBKT];
    for (int i = threadIdx.x; i < NBKT; i += blockDim.x) h[i] = 0;
    if (blockIdx.x == 0)
        for (int i = threadIdx.x; i < 3 * NSLOT * 64; i += blockDim.x) stats[i] = 0.0f;
    __syncthreads();
    int base = blockIdx.x * CHUNK;
    int end  = min(base + CHUNK, NEDGES);
    for (int e = base + threadIdx.x * 4; e < end; e += blockDim.x * 4) {
        int4 d = *reinterpret_cast<const int4*>(dst + e);
        atomicAdd(&h[d.x >> BKT_SHIFT], 1);
        atomicAdd(&h[d.y >> BKT_SHIFT], 1);
        atomicAdd(&h[d.z >> BKT_SHIFT], 1);
        atomicAdd(&h[d.w >> BKT_SHIFT], 1);
    }
    __syncthreads();
    for (int i = threadIdx.x; i < NBKT; i += blockDim.x)
        blk_hist_T[i * NBLK_E + blockIdx.x] = h[i];   // [bucket][block]
}

// Per-bucket exclusive scan across blocks + bucket totals as by-product.
__global__ void scan_blocks(const int* __restrict__ blk_hist_T,
                            int* __restrict__ blk_off, int* __restrict__ bucket_total) {
    __shared__ int wsum[4];
    int b = blockIdx.x;
    int i = threadIdx.x;
    int v = (i < NBLK_E) ? blk_hist_T[b * NBLK_E + i] : 0;
    int excl = block_excl_scan<256>(v, wsum);
    if (i < NBLK_E) blk_off[i * NBKT + b] = excl;     // [block][bucket]
    if (i == 255) bucket_total[b] = excl + v;
}

// Pass 2: scatter edges into bucket segments (packed dst_local<<23 | src).
__global__ void bucket_scatter(const int* __restrict__ src, const int* __restrict__ dst,
                               const int* __restrict__ blk_off, const int* __restrict__ bucket_total,
                               unsigned int* __restrict__ staged) {
    __shared__ int cur[NBKT];
    __shared__ int wsum[8];
    int v = (threadIdx.x < NBKT) ? bucket_total[threadIdx.x] : 0;
    int bbase = block_excl_scan<512>(v, wsum);
    if (threadIdx.x < NBKT)
        cur[threadIdx.x] = bbase + blk_off[blockIdx.x * NBKT + threadIdx.x];
    __syncthreads();
    int base = blockIdx.x * CHUNK;
    int end  = min(base + CHUNK, NEDGES);
    for (int e = base + threadIdx.x * 4; e < end; e += blockDim.x * 4) {
        int4 d = *reinterpret_cast<const int4*>(dst + e);
        int4 s = *reinterpret_cast<const int4*>(src + e);
        int p0 = atomicAdd(&cur[d.x >> BKT_SHIFT], 1);
        staged[p0] = ((unsigned)(d.x & (BKT_SIZE - 1)) << 23) | (unsigned)s.x;
        int p1 = atomicAdd(&cur[d.y >> BKT_SHIFT], 1);
        staged[p1] = ((unsigned)(d.y & (BKT_SIZE - 1)) << 23) | (unsigned)s.y;
        int p2 = atomicAdd(&cur[d.z >> BKT_SHIFT], 1);
        staged[p2] = ((unsigned)(d.z & (BKT_SIZE - 1)) << 23) | (unsigned)s.z;
        int p3 = atomicAdd(&cur[d.w >> BKT_SHIFT], 1);
        staged[p3] = ((unsigned)(d.w & (BKT_SIZE - 1)) << 23) | (unsigned)s.w;
    }
}

// Pass 3: one block per bucket -> exact CSR (row_ptr + node-sorted col).
__global__ void csr_finalize(const unsigned int* __restrict__ staged,
                             const int* __restrict__ bucket_total,
                             int* __restrict__ row_ptr, int* __restrict__ col) {
    __shared__ int nh[BKT_SIZE];
    __shared__ int cur[BKT_SIZE];
    __shared__ int wsum[8];
    __shared__ int sBeg, sEnd;
    int b = blockIdx.x;

    nh[threadIdx.x] = 0;                      // covered by scan's leading barrier
    int v = (threadIdx.x < NBKT) ? bucket_total[threadIdx.x] : 0;
    int excl = block_excl_scan<512>(v, wsum);
    if (threadIdx.x == b) { sBeg = excl; sEnd = excl + v; }
    __syncthreads();
    int beg = sBeg, end = sEnd;

    for (int e = beg + threadIdx.x; e < end; e += blockDim.x)
        atomicAdd(&nh[staged[e] >> 23], 1);
    __syncthreads();

    int hv = nh[threadIdx.x];
    int hexcl = block_excl_scan<512>(hv, wsum);

    int node = b * BKT_SIZE + threadIdx.x;
    if (node < NNODES) row_ptr[node] = beg + hexcl;
    if (b == 0 && threadIdx.x == 0) row_ptr[NNODES] = NEDGES;
    cur[threadIdx.x] = hexcl;
    __syncthreads();

    for (int e = beg + threadIdx.x; e < end; e += blockDim.x) {
        unsigned pk = staged[e];
        int l = (int)(pk >> 23);
        int p = atomicAdd(&cur[l], 1);          // LDS atomic only
        col[beg + p] = (int)(pk & 0x7FFFFF);
    }
}

// ---------------------------------------------------------------------------
__device__ __forceinline__ void unpack8(uint4 v, float* f) {
    float2 a = __half22float2(*(const __half2*)&v.x);
    float2 b = __half22float2(*(const __half2*)&v.y);
    float2 c = __half22float2(*(const __half2*)&v.z);
    float2 d = __half22float2(*(const __half2*)&v.w);
    f[0] = a.x; f[1] = a.y; f[2] = b.x; f[3] = b.y;
    f[4] = c.x; f[5] = c.y; f[6] = d.x; f[7] = d.y;
}

// Row load: fp16 rows as 1-2 uint4 (8 halves each), fp32 rows as float4s.
template<int CI, int SI, bool H>
__device__ __forceinline__ void load_row2(const void* base, long node, float* r) {
    if constexpr (H) {
        const __half* p = (const __half*)base + node * SI;
        float t[SI > 8 ? 16 : 8];
        uint4 v0 = *(const uint4*)p;
        unpack8(v0, t);
        if constexpr (SI > 8) {
            uint4 v1 = *(const uint4*)(p + 8);
            unpack8(v1, t + 8);
        }
#pragma unroll
        for (int c = 0; c < CI; c++) r[c] = t[c];
    } else {
        const float* p = (const float*)base + node * SI;
#pragma unroll
        for (int c = 0; c < CI; c += 4) {
            float4 v = *(const float4*)(p + c);
            r[c] = v.x; r[c+1] = v.y; r[c+2] = v.z; r[c+3] = v.w;
        }
    }
}

// ---------------------------------------------------------------------------
// Lane-group fused layer (round-2 structure, proven): G lanes/node, gather
// pipeline in registers, butterfly reduce, LDS weights padded to CI+1.
// Round-10 change: fp16 intermediate tables (L2-resident -> gather latency
// ~200cy instead of LLC ~600cy; half the 16B loads). All math fp32.
template<int CI, int SI, int CO, int SO, int G,
         bool IN_HALF, bool OUT_HALF, bool IN_AFFINE, bool DO_STATS>
__global__ void layer_kernel(const int* __restrict__ row_ptr, const int* __restrict__ col,
                             const void* __restrict__ h,
                             const float* __restrict__ ssum_in, const float* __restrict__ ssq_in,
                             const float* __restrict__ g_in, const float* __restrict__ b_in,
                             const float* __restrict__ wl, const float* __restrict__ bl,
                             const float* __restrict__ wr,
                             void* __restrict__ y,
                             float* __restrict__ stat_sum, float* __restrict__ stat_sq) {
    constexpr int NPB = 256 / G;             // nodes per block
    constexpr int OPL = (CO + G - 1) / G;    // outputs per lane
    constexpr int PCI = CI + 1;              // padded LDS stride

    __shared__ float sWl[CO * PCI];
    __shared__ float sWr[CO * PCI];
    __shared__ float sBl[CO];
    __shared__ float sSc[CI];
    __shared__ float sSh[CI];
    __shared__ float sSumR[CI];
    __shared__ float sSqR[CI];
    __shared__ float red_sum[CO];
    __shared__ float red_sq[CO];

    for (int i = threadIdx.x; i < CO * CI; i += blockDim.x) {
        int o = i / CI, c = i - o * CI;
        sWl[o * PCI + c] = wl[i];
        sWr[o * PCI + c] = wr[i];
    }
    if (threadIdx.x < CO) {
        sBl[threadIdx.x] = bl[threadIdx.x];
        if (DO_STATS) { red_sum[threadIdx.x] = 0.0f; red_sq[threadIdx.x] = 0.0f; }
    }
    if (IN_AFFINE && threadIdx.x < CI) { sSumR[threadIdx.x] = 0.0f; sSqR[threadIdx.x] = 0.0f; }
    __syncthreads();
    if (IN_AFFINE) {
        int c = threadIdx.x & 31, sl = threadIdx.x >> 5;    // 8 slices over NSLOT
        if (c < CI) {
            float ps = 0.0f, pq = 0.0f;
#pragma unroll
            for (int s = sl; s < NSLOT; s += 8) {
                ps += ssum_in[s * 64 + c];
                pq += ssq_in[s * 64 + c];
            }
            atomicAdd(&sSumR[c], ps);
            atomicAdd(&sSqR[c], pq);
        }
        __syncthreads();
        if (threadIdx.x < CI) {
            float m  = sSumR[threadIdx.x] * (1.0f / NNODES);
            float vv = sSqR[threadIdx.x] * (1.0f / NNODES) - m * m;
            float s  = g_in[threadIdx.x] / sqrtf(vv + BN_EPS);
            sSc[threadIdx.x] = s;
            sSh[threadIdx.x] = b_in[threadIdx.x] - m * s;
        }
    }
    __syncthreads();

    int node = blockIdx.x * NPB + (threadIdx.x / G);
    int g    = threadIdx.x & (G - 1);
    bool valid = node < NNODES;

    float acc[CI];
#pragma unroll
    for (int c = 0; c < CI; c++) acc[c] = 0.0f;

    int beg = 0, end = 0;
    if (valid) {
        beg = row_ptr[node];
        end = row_ptr[node + 1];
        int j = beg + g;
        if constexpr (CI <= 8) {
            // 4 rows in flight (register-safe only for small rows)
            for (; j + 3 * G < end; j += 4 * G) {
                int i0 = col[j], i1 = col[j + G], i2 = col[j + 2 * G], i3 = col[j + 3 * G];
                float r0[CI], r1[CI], r2[CI], r3[CI];
                load_row2<CI, SI, IN_HALF>(h, i0, r0);
                load_row2<CI, SI, IN_HALF>(h, i1, r1);
                load_row2<CI, SI, IN_HALF>(h, i2, r2);
                load_row2<CI, SI, IN_HALF>(h, i3, r3);
#pragma unroll
                for (int c = 0; c < CI; c++) acc[c] += (r0[c] + r1[c]) + (r2[c] + r3[c]);
            }
        }
        // 2 rows in flight
        for (; j + G < end; j += 2 * G) {
            int i0 = col[j], i1 = col[j + G];
            float r0[CI], r1[CI];
            load_row2<CI, SI, IN_HALF>(h, i0, r0);
            load_row2<CI, SI, IN_HALF>(h, i1, r1);
#pragma unroll
            for (int c = 0; c < CI; c++) acc[c] += r0[c] + r1[c];
        }
        if (j < end) {
            float r0[CI];
            load_row2<CI, SI, IN_HALF>(h, col[j], r0);
#pragma unroll
            for (int c = 0; c < CI; c++) acc[c] += r0[c];
        }
    }

    // butterfly: all G lanes end with the full neighbor sum
#pragma unroll
    for (int m = 1; m < G; m <<= 1)
#pragma unroll
        for (int c = 0; c < CI; c++) acc[c] += __shfl_xor(acc[c], m);

    float out[OPL];
    float nrm2 = 0.0f;
    if (valid) {
        float ic = 1.0f / fmaxf((float)(end - beg), 1.0f);
        float xin[CI];
        load_row2<CI, SI, IN_HALF>(h, node, xin);
        float agg[CI];
#pragma unroll
        for (int c = 0; c < CI; c++) {
            float a  = acc[c] * ic;
            float xv = xin[c];
            if (IN_AFFINE) {
                a  = a  * sSc[c] + sSh[c];
                xv = xv * sSc[c] + sSh[c];
            }
            agg[c] = a;
            xin[c] = xv;
        }
#pragma unroll
        for (int k = 0; k < OPL; k++) {
            int o = g * OPL + k;
            float v = 0.0f;
            if (o < CO) {
                v = sBl[o];
#pragma unroll
                for (int c = 0; c < CI; c++)
                    v += sWl[o * PCI + c] * agg[c] + sWr[o * PCI + c] * xin[c];
            }
            out[k] = v;
            nrm2 += v * v;
        }
    }
#pragma unroll
    for (int m = 1; m < G; m <<= 1) nrm2 += __shfl_xor(nrm2, m);

    if (valid) {
        float inv_nrm = 1.0f / fmaxf(sqrtf(nrm2), L2_EPS);
#pragma unroll
        for (int k = 0; k < OPL; k++) {
            int o = g * OPL + k;
            float v = (o < CO) ? fmaxf(out[k] * inv_nrm, 0.0f) : 0.0f;  // L2 norm + ReLU
            if constexpr (OUT_HALF) {
                if (o < SO) ((__half*)y)[(long)node * SO + o] = __float2half_rn(v);  // pad -> 0
            } else {
                if (o < CO) ((float*)y)[(long)node * SO + o] = v;
            }
            if (DO_STATS && o < CO) {
                atomicAdd(&red_sum[o], v);
                atomicAdd(&red_sq[o], v * v);
            }
        }
    }

    if (DO_STATS) {
        __syncthreads();
        if (threadIdx.x < CO) {
            int slot = blockIdx.x & (NSLOT - 1);
            atomicAdd(&stat_sum[slot * 64 + threadIdx.x], red_sum[threadIdx.x]);
            atomicAdd(&stat_sq [slot * 64 + threadIdx.x], red_sq[threadIdx.x]);
        }
    }
}

// ---------------------------------------------------------------------------
extern "C" void kernel_launch(void* const* d_in, const int* in_sizes, int n_in,
                              void* d_out, int out_size, void* d_ws, size_t ws_size,
                              hipStream_t stream) {
    const float* x   = (const float*)d_in[0];
    const int*   ei  = (const int*)d_in[1];
    const int*   src = ei;
    const int*   dst = ei + NEDGES;

    const float* w1l = (const float*)d_in[2];
    const float* b1l = (const float*)d_in[3];
    const float* w1r = (const float*)d_in[4];
    const float* w2l = (const float*)d_in[5];
    const float* b2l = (const float*)d_in[6];
    const float* w2r = (const float*)d_in[7];
    const float* w3l = (const float*)d_in[8];
    const float* b3l = (const float*)d_in[9];
    const float* w3r = (const float*)d_in[10];
    const float* w4l = (const float*)d_in[11];
    const float* b4l = (const float*)d_in[12];
    const float* w4r = (const float*)d_in[13];
    const float* g1  = (const float*)d_in[14];
    const float* be1 = (const float*)d_in[15];
    const float* g2  = (const float*)d_in[16];
    const float* be2 = (const float*)d_in[17];
    const float* g3  = (const float*)d_in[18];
    const float* be3 = (const float*)d_in[19];

    char* w = (char*)d_ws;
    int* blk_hist     = (int*)w;  w += NBLK_E * NBKT * 4;
    int* blk_off      = (int*)w;  w += NBLK_E * NBKT * 4;
    int* bucket_total = (int*)w;  w += 256 * 4;
    int* row_ptr      = (int*)w;  w += (NNODES + 8) * 4;
    int* col          = (int*)w;  w += NEDGES * 4;
    __half* hA        = (__half*)w; w += NNODES * 16 * 4;  // fp16 tables (slab over-alloc)
    __half* hB        = (__half*)w; w += NNODES * 16 * 4;  // aliased by staged
    float* stats      = (float*)w; w += 3 * NSLOT * 64 * 4;
    unsigned int* staged = (unsigned int*)hB;  // dead before hB is written

    float* ssum1 = stats + 0 * NSLOT * 64, *ssq1 = ssum1 + 32;
    float* ssum2 = stats + 1 * NSLOT * 64, *ssq2 = ssum2 + 32;
    float* ssum3 = stats + 2 * NSLOT * 64, *ssq3 = ssum3 + 32;

    // atomic-free CSR build (LDS atomics only), 4 launches — round-2 proven
    hist_kernel   <<<NBLK_E, 512, 0, stream>>>(dst, blk_hist, stats);
    scan_blocks   <<<NBKT, 256, 0, stream>>>(blk_hist, blk_off, bucket_total);
    bucket_scatter<<<NBLK_E, 512, 0, stream>>>(src, dst, blk_off, bucket_total, staged);
    csr_finalize  <<<NBKT, 512, 0, stream>>>(staged, bucket_total, row_ptr, col);

    const int NLB = (NNODES * 8 + 255) / 256;   // 3125 blocks (G=8)

    // layer 1: 4 -> 6; in fp32 x (SI=4), out fp16 hA (SO=8 halves), +stats
    layer_kernel<4, 4, 6, 8, 8, false, true, false, true><<<NLB, 256, 0, stream>>>(
        row_ptr, col, x, nullptr, nullptr, nullptr, nullptr,
        w1l, b1l, w1r, hA, ssum1, ssq1);

    // layer 2: 6 -> 8; in fp16 hA (SI=8, 1 load/row), BN1 in-block, out fp16 hB, +stats
    layer_kernel<6, 8, 8, 8, 8, true, true, true, true><<<NLB, 256, 0, stream>>>(
        row_ptr, col, hA, ssum1, ssq1, g1, be1,
        w2l, b2l, w2r, hB, ssum2, ssq2);

    // layer 3: 8 -> 16; in fp16 hB (SI=8, 1 load/row), BN2, out fp16 hA, +stats
    layer_kernel<8, 8, 16, 16, 8, true, true, true, true><<<NLB, 256, 0, stream>>>(
        row_ptr, col, hB, ssum2, ssq2, g2, be2,
        w3l, b3l, w3r, hA, ssum3, ssq3);

    // layer 4: 16 -> 32; in fp16 hA (SI=16, 2 loads/row), BN3, ReLU -> fp32 d_out
    layer_kernel<16, 16, 32, 32, 8, true, false, true, false><<<NLB, 256, 0, stream>>>(
        row_ptr, col, hA, ssum3, ssq3, g3, be3,
        w4l, b4l, w4r, d_out, nullptr, nullptr);
}